// Round 16
// baseline (286.520 us; speedup 1.0000x reference)
//
#include <hip/hip_runtime.h>

typedef short bf16x8 __attribute__((ext_vector_type(8)));
typedef float f32x4 __attribute__((ext_vector_type(4)));

// Problem constants
// B=16, N=1024, D=768, H=12, HD=64, NUM_BUCKETS=49, SCALE=0.125
// Q is pre-scaled by SCALE*log2(e) so softmax runs in exp2 domain.
#define QSCALE 0.1803368801111204f

__device__ __forceinline__ unsigned short f2bf(float f){
  unsigned u = __float_as_uint(f);
  u = (u + 0x7fffu + ((u >> 16) & 1u)) >> 16;   // round-nearest-even
  return (unsigned short)u;
}
__device__ __forceinline__ f32x4 mfma16(bf16x8 a, bf16x8 b, f32x4 c){
  return __builtin_amdgcn_mfma_f32_16x16x32_bf16(a, b, c, 0, 0, 0);
}
__device__ __forceinline__ void gload_lds16(const void* g, void* l){
  __builtin_amdgcn_global_load_lds((__attribute__((address_space(1))) void*)(g),
                                   (__attribute__((address_space(3))) void*)(l), 16, 0, 0);
}
__device__ __forceinline__ unsigned cvt_pk_bf16(float lo, float hi){
  unsigned r;
  asm("v_cvt_pk_bf16_f32 %0, %1, %2" : "=v"(r) : "v"(lo), "v"(hi));
  return r;
}
// v_exp_f32 computes 2^x natively on gfx950 (cdna4_isa §3)
__device__ __forceinline__ float exp2_fast(float x){
  float r;
  asm("v_exp_f32 %0, %1" : "=v"(r) : "v"(x));
  return r;
}

// ---------------------------------------------------------------------------
// prep: f32 -> bf16 conversions + rp_bucket -> pre-swizzled byte offsets
// ---------------------------------------------------------------------------
__global__ __launch_bounds__(256) void prep_kernel(
    const float* __restrict__ x, const float* __restrict__ qw,
    const float* __restrict__ pw, const int* __restrict__ rp,
    unsigned short* __restrict__ xb, unsigned short* __restrict__ wb,
    unsigned short* __restrict__ pwb, unsigned char* __restrict__ rp8){
  const int T1 = 3145728;            // 16384*768/4
  const int T2 = T1 + 442368;        // + 2304*768/4
  const int T3 = T2 + 147456;        // + 768*768/4
  const int T4 = T3 + 262144;        // + 1024*1024/4
  for (int t = blockIdx.x * 256 + threadIdx.x; t < T4; t += gridDim.x * 256){
    if (t < T3){
      const float4* src; ushort4* dst; int off;
      if (t < T1){ src = (const float4*)x;  dst = (ushort4*)xb;  off = t; }
      else if (t < T2){ src = (const float4*)qw; dst = (ushort4*)wb;  off = t - T1; }
      else { src = (const float4*)pw; dst = (ushort4*)pwb; off = t - T2; }
      float4 v = src[off];
      ushort4 u;
      u.x = f2bf(v.x); u.y = f2bf(v.y); u.z = f2bf(v.z); u.w = f2bf(v.w);
      dst[off] = u;
    } else {
      int off = t - T3;
      int4 v = ((const int4*)rp)[off];
      int row = (off * 4) >> 10;               // all 4 j's share the row
      int sw = (row & 7) << 4;
      uchar4 u;
      u.x = (unsigned char)((v.x << 1) ^ sw);
      u.y = (unsigned char)((v.y << 1) ^ sw);
      u.z = (unsigned char)((v.z << 1) ^ sw);
      u.w = (unsigned char)((v.w << 1) ^ sw);
      ((uchar4*)rp8)[off] = u;
    }
  }
}

// ---------------------------------------------------------------------------
// 256x128 8-phase GEMM core (counted-vmcnt schedule, BK=32).
// 512 threads = 8 waves (2 wr x 4 wc); per-wave C-tile 128x32 = acc[8][2].
// acc = 64 VGPR -> fits the 128-VGPR cap of __launch_bounds__(512,4)
// = 4 waves/EU = 2 blocks/CU (the R14/R15 core was silently 1 block/CU).
// LDS 48KB: A dbuf 2x16KB + B dbuf 2x8KB.
// Tiles: [lines][128B], line = 2 rows of 32 bf16, chunk XOR-swizzle (line&7)
// on stage source and read. MFMA operands swapped (b first).
// vmcnt(1) at phase 0/4 boundaries only (B-next stays in flight).
// ---------------------------------------------------------------------------
__device__ __forceinline__ void stage_a_half(
    const unsigned short* __restrict__ M, int r0, int K, int kt, int half,
    char* dst, int tid){
  int ci = half * 512 + tid;          // 1024 chunks of 16B (256 rows)
  int lr = ci >> 3, s = ci & 7;
  int cc = s ^ (lr & 7);
  int grow = lr * 2 + (cc >> 2);
  int gk = (cc & 3) * 8;
  gload_lds16(M + (size_t)(r0 + grow) * K + kt * 32 + gk, dst + ci * 16);
}
__device__ __forceinline__ void stage_b(
    const unsigned short* __restrict__ M, int r0, int K, int kt,
    char* dst, int tid){
  int ci = tid;                       // 512 chunks of 16B (128 rows)
  int lr = ci >> 3, s = ci & 7;
  int cc = s ^ (lr & 7);
  int grow = lr * 2 + (cc >> 2);
  int gk = (cc & 3) * 8;
  gload_lds16(M + (size_t)(r0 + grow) * K + kt * 32 + gk, dst + ci * 16);
}

__device__ __forceinline__ void gemm_core_mn(
    const unsigned short* __restrict__ A, const unsigned short* __restrict__ Bm,
    int m0, int n0, int K, char* smem, f32x4 (&acc)[8][2]){
  const int tid = threadIdx.x, lane = tid & 63;
  const int w = tid >> 6, g = lane >> 4, r16 = lane & 15;
  const int wr = w >> 2, wc = w & 3;
  const int NT = K >> 5;
  char* Ab0 = smem;            char* Ab1 = smem + 16384;
  char* Bb0 = smem + 32768;    char* Bb1 = smem + 40960;

  // prologue: B(0), A(0), B(1) -> 4 outstanding loads/thread
  stage_b(Bm, n0, K, 0, Bb0, tid);
  stage_a_half(A, m0, K, 0, 0, Ab0, tid);
  stage_a_half(A, m0, K, 0, 1, Ab0, tid);
  stage_b(Bm, n0, K, 1, Bb1, tid);

  const int arb = wr * 128 + r16;
  const int brb = wc * 32 + r16;
  bf16x8 bq[2];

#define LOADB_(buf) { \
  _Pragma("unroll") \
  for (int ni = 0; ni < 2; ni++){ \
    int row = brb + ni * 16; int lr = row >> 1; \
    bq[ni] = *(const bf16x8*)((buf) + lr * 128 + ((((row & 1) << 6) + g * 16) ^ ((lr & 7) << 4))); } }
#define QUAD_(buf, p) { \
  int ra = arb + (2 * (p)) * 16; int rb = ra + 16; \
  int la = ra >> 1, lb = rb >> 1; \
  bf16x8 afa = *(const bf16x8*)((buf) + la * 128 + ((((ra & 1) << 6) + g * 16) ^ ((la & 7) << 4))); \
  bf16x8 afb = *(const bf16x8*)((buf) + lb * 128 + ((((rb & 1) << 6) + g * 16) ^ ((lb & 7) << 4))); \
  __builtin_amdgcn_s_setprio(1); \
  _Pragma("unroll") \
  for (int ni = 0; ni < 2; ni++){ \
    acc[2 * (p)][ni]     = mfma16(bq[ni], afa, acc[2 * (p)][ni]); \
    acc[2 * (p) + 1][ni] = mfma16(bq[ni], afb, acc[2 * (p) + 1][ni]); } \
  __builtin_amdgcn_s_setprio(0); }

  for (int T = 0; T < NT; T += 2){
    int t2 = T + 2, t3 = T + 3;
    if (t2 >= NT) t2 -= NT;
    if (t3 >= NT) t3 -= NT;
    // loop top: B(T),A(T) landed (leave B(T+1) in flight)
    asm volatile("s_waitcnt vmcnt(1) lgkmcnt(0)" ::: "memory");
    __builtin_amdgcn_s_barrier();
    __builtin_amdgcn_sched_barrier(0);
    // ph0
    stage_a_half(A, m0, K, T + 1, 0, Ab1, tid);
    LOADB_(Bb0); QUAD_(Ab0, 0);
    // ph1
    stage_a_half(A, m0, K, T + 1, 1, Ab1, tid);
    QUAD_(Ab0, 1);
    asm volatile("s_waitcnt lgkmcnt(0)" ::: "memory");
    __builtin_amdgcn_s_barrier();            // frees Bb0 for restage
    __builtin_amdgcn_sched_barrier(0);
    // ph2
    stage_b(Bm, n0, K, t2, Bb0, tid);
    QUAD_(Ab0, 2);
    // ph3
    QUAD_(Ab0, 3);
    // B(T+1),A(T+1) landed (leave B(t2) in flight)
    asm volatile("s_waitcnt vmcnt(1) lgkmcnt(0)" ::: "memory");
    __builtin_amdgcn_s_barrier();
    __builtin_amdgcn_sched_barrier(0);
    // ph4
    stage_a_half(A, m0, K, t2, 0, Ab0, tid);
    LOADB_(Bb1); QUAD_(Ab1, 0);
    // ph5
    stage_a_half(A, m0, K, t2, 1, Ab0, tid);
    QUAD_(Ab1, 1);
    asm volatile("s_waitcnt lgkmcnt(0)" ::: "memory");
    __builtin_amdgcn_s_barrier();            // frees Bb1 for restage
    __builtin_amdgcn_sched_barrier(0);
    // ph6
    stage_b(Bm, n0, K, t3, Bb1, tid);
    QUAD_(Ab1, 2);
    // ph7
    QUAD_(Ab1, 3);
  }
#undef LOADB_
#undef QUAD_
}

// ---------------------------------------------------------------------------
// QKV projection (256x128 8-phase, 2 blocks/CU): qkv = x @ qkv_w^T ; route to
// Q(*QSCALE)[B,H,N,HD], K[B,H,N,HD], V^T[B,H,HD,N], bf16.
// Each 128-wide n-tile lies wholly in one of Q/K/V (768 = 6 x 128).
// ---------------------------------------------------------------------------
__global__ __launch_bounds__(512, 4) void qkv_gemm(
    const unsigned short* __restrict__ xb, const unsigned short* __restrict__ wb,
    unsigned short* __restrict__ q_s, unsigned short* __restrict__ k_s,
    unsigned short* __restrict__ v_t){
  __shared__ __align__(16) char smem[49152];
  f32x4 acc[8][2];
  #pragma unroll
  for (int i = 0; i < 8; i++)
    #pragma unroll
    for (int j = 0; j < 2; j++){
      acc[i][j][0] = 0.f; acc[i][j][1] = 0.f; acc[i][j][2] = 0.f; acc[i][j][3] = 0.f;
    }
  const int m0 = blockIdx.y * 256, n0 = blockIdx.x * 128;
  gemm_core_mn(xb, wb, m0, n0, 768, smem, acc);

  const int tid = threadIdx.x, lane = tid & 63, w = tid >> 6;
  const int g = lane >> 4, r16 = lane & 15;
  const int wr = w >> 2, wc = w & 3;
  const int sel = n0 / 768;                       // block-uniform
  #pragma unroll
  for (int mi = 0; mi < 8; mi++){
    int grow = m0 + wr * 128 + mi * 16 + r16;     // 0..16383 = [16][1024]
    int bb = grow >> 10, ii = grow & 1023;
    #pragma unroll
    for (int ni = 0; ni < 2; ni++){
      int gcol0 = n0 + wc * 32 + ni * 16 + 4 * g; // 4-aligned, within one head
      int rem = gcol0 - sel * 768;
      int h = rem >> 6, hd0 = rem & 63;
      size_t base = ((size_t)(bb * 12 + h)) << 16;   // *1024*64
      f32x4 v = acc[mi][ni];
      if (sel == 0){
        ushort4 u;
        u.x = f2bf(v[0] * QSCALE); u.y = f2bf(v[1] * QSCALE);
        u.z = f2bf(v[2] * QSCALE); u.w = f2bf(v[3] * QSCALE);
        *(ushort4*)(q_s + base + ((size_t)ii << 6) + hd0) = u;
      } else if (sel == 1){
        ushort4 u;
        u.x = f2bf(v[0]); u.y = f2bf(v[1]); u.z = f2bf(v[2]); u.w = f2bf(v[3]);
        *(ushort4*)(k_s + base + ((size_t)ii << 6) + hd0) = u;
      } else {
        #pragma unroll
        for (int r = 0; r < 4; r++)
          v_t[base + ((size_t)(hd0 + r) << 10) + ii] = f2bf(v[r]);
      }
    }
  }
}

// ---------------------------------------------------------------------------
// Flash attention with relative-position bias (exp2-domain online softmax,
// defer-max THR=8, pre-swizzled bucket byte offsets, bf16 bias table).
// R7/R13 champion: 64 q-rows/block, 4 waves x 16 rows, LDS 32768 B. FROZEN.
// ---------------------------------------------------------------------------
__global__ __launch_bounds__(256) void attn_kernel(
    const unsigned short* __restrict__ q_s, const unsigned short* __restrict__ k_s,
    const unsigned short* __restrict__ v_t, const unsigned char* __restrict__ rp8,
    const float* __restrict__ rpe, unsigned short* __restrict__ ao){
  __shared__ __align__(16) char smem[32768];
  const int tid = threadIdx.x, lane = tid & 63, w = tid >> 6;
  const int g = lane >> 4, r16 = lane & 15;
  const int qb = blockIdx.x, bh = blockIdx.y;
  const size_t bh_base = (size_t)bh << 16;   // *1024*64 elements

  const int i_loc = w * 16 + r16;
  const size_t qoff = bh_base + ((size_t)(qb * 64 + i_loc) << 6);
  bf16x8 qf0 = *(const bf16x8*)(q_s + qoff + g * 8);
  bf16x8 qf1 = *(const bf16x8*)(q_s + qoff + 32 + g * 8);

  // bias[i][c] = q_i . rpe_c via MFMA; bf16, swizzled; wave-private
  char* bias_lds = smem + 24576;
  const int s16 = (r16 & 7) << 4;
  #pragma unroll
  for (int jt = 0; jt < 4; jt++){
    int crow = jt * 16 + r16;
    bf16x8 a0, a1;
    #pragma unroll
    for (int e = 0; e < 8; e++){ a0[e] = 0; a1[e] = 0; }
    if (crow < 49){
      const float* rr = rpe + crow * 64 + g * 8;
      float4 x0 = *(const float4*)(rr);
      float4 x1 = *(const float4*)(rr + 4);
      float4 y0 = *(const float4*)(rr + 32);
      float4 y1 = *(const float4*)(rr + 36);
      a0[0]=f2bf(x0.x); a0[1]=f2bf(x0.y); a0[2]=f2bf(x0.z); a0[3]=f2bf(x0.w);
      a0[4]=f2bf(x1.x); a0[5]=f2bf(x1.y); a0[6]=f2bf(x1.z); a0[7]=f2bf(x1.w);
      a1[0]=f2bf(y0.x); a1[1]=f2bf(y0.y); a1[2]=f2bf(y0.z); a1[3]=f2bf(y0.w);
      a1[4]=f2bf(y1.x); a1[5]=f2bf(y1.y); a1[6]=f2bf(y1.z); a1[7]=f2bf(y1.w);
    }
    f32x4 z = {0.f, 0.f, 0.f, 0.f};
    z = mfma16(a0, qf0, z);
    z = mfma16(a1, qf1, z);
    uint2 u; u.x = cvt_pk_bf16(z[0], z[1]); u.y = cvt_pk_bf16(z[2], z[3]);
    *(uint2*)(bias_lds + i_loc * 128 + ((jt * 32 + 8 * g) ^ s16)) = u;
  }

  unsigned short* ks = (unsigned short*)smem;
  unsigned short* vs = (unsigned short*)(smem + 8192);
  char* pbuf = smem + 16384 + w * 2048;
  const char* browb = bias_lds + i_loc * 128;

  const int ci0 = tid, ci1 = 256 + tid;
  const int row0 = ci0 >> 3, sc0 = (ci0 & 7) ^ (row0 & 7);
  const int row1 = ci1 >> 3, sc1 = (ci1 & 7) ^ (row1 & 7);
  const char* kp0 = (const char*)(k_s + bh_base) + row0 * 128 + sc0 * 16;
  const char* kp1 = (const char*)(k_s + bh_base) + row1 * 128 + sc1 * 16;
  const char* vp0 = (const char*)(v_t + bh_base) + row0 * 2048 + sc0 * 16;
  const char* vp1 = (const char*)(v_t + bh_base) + row1 * 2048 + sc1 * 16;
  char* kl0 = (char*)smem + w * 1024;
  char* kl1 = (char*)smem + 4096 + w * 1024;
  char* vl0 = (char*)smem + 8192 + w * 1024;
  char* vl1 = (char*)smem + 12288 + w * 1024;
  const unsigned char* rprow = rp8 + ((size_t)(qb * 64 + i_loc) << 10);

  f32x4 o[4];
  #pragma unroll
  for (int dt = 0; dt < 4; dt++){ o[dt][0]=0.f; o[dt][1]=0.f; o[dt][2]=0.f; o[dt][3]=0.f; }
  float m_i = -INFINITY, l_i = 0.f;

  for (int kb = 0; kb < 16; kb++){
    __syncthreads();
    gload_lds16(kp0, kl0);
    gload_lds16(kp1, kl1);
    gload_lds16(vp0, vl0);
    gload_lds16(vp1, vl1);
    kp0 += 8192; kp1 += 8192; vp0 += 128; vp1 += 128;
    __syncthreads();

    f32x4 st[4];
    #pragma unroll
    for (int jt = 0; jt < 4; jt++){
      int krow = jt * 16 + r16;
      int sw = (krow & 7) << 4;
      bf16x8 ka0 = *(const bf16x8*)((char*)ks + krow * 128 + ((g * 16) ^ sw));
      bf16x8 ka1 = *(const bf16x8*)((char*)ks + krow * 128 + ((64 + g * 16) ^ sw));
      f32x4 z = {0.f, 0.f, 0.f, 0.f};
      z = mfma16(ka0, qf0, z);
      z = mfma16(ka1, qf1, z);
      st[jt] = z;
    }
    #pragma unroll
    for (int jt = 0; jt < 4; jt++){
      unsigned bu = *(const unsigned*)(rprow + kb * 64 + jt * 16 + g * 4);
      st[jt][0] += __uint_as_float((unsigned)*(const unsigned short*)(browb + (bu & 0xff)) << 16);
      st[jt][1] += __uint_as_float((unsigned)*(const unsigned short*)(browb + ((bu >> 8) & 0xff)) << 16);
      st[jt][2] += __uint_as_float((unsigned)*(const unsigned short*)(browb + ((bu >> 16) & 0xff)) << 16);
      st[jt][3] += __uint_as_float((unsigned)*(const unsigned short*)(browb + (bu >> 24)) << 16);
    }
    float tmax = -INFINITY;
    #pragma unroll
    for (int jt = 0; jt < 4; jt++)
      tmax = fmaxf(tmax, fmaxf(fmaxf(st[jt][0], st[jt][1]), fmaxf(st[jt][2], st[jt][3])));
    tmax = fmaxf(tmax, __shfl_xor(tmax, 16));
    tmax = fmaxf(tmax, __shfl_xor(tmax, 32));
    const bool skip = __all(tmax <= m_i + 8.f);
    if (!skip){
      float mnew = fmaxf(m_i, tmax);
      float alpha = exp2_fast(m_i - mnew);
      m_i = mnew;
      l_i *= alpha;
      float af[4];
      #pragma unroll
      for (int r = 0; r < 4; r++) af[r] = __shfl(alpha, 4 * g + r);
      #pragma unroll
      for (int dt = 0; dt < 4; dt++){
        o[dt][0] *= af[0]; o[dt][1] *= af[1]; o[dt][2] *= af[2]; o[dt][3] *= af[3];
      }
    }
    #pragma unroll
    for (int jt = 0; jt < 4; jt++){
      float p0 = exp2_fast(st[jt][0] - m_i);
      float p1 = exp2_fast(st[jt][1] - m_i);
      float p2 = exp2_fast(st[jt][2] - m_i);
      float p3 = exp2_fast(st[jt][3] - m_i);
      l_i += (p0 + p1) + (p2 + p3);
      uint2 u; u.x = cvt_pk_bf16(p0, p1); u.y = cvt_pk_bf16(p2, p3);
      *(uint2*)(pbuf + r16 * 128 + ((jt * 32 + g * 8) ^ ((r16 & 7) << 4))) = u;
    }
    #pragma unroll
    for (int kt = 0; kt < 2; kt++){
      bf16x8 pa = *(const bf16x8*)(pbuf + r16 * 128 + ((kt * 64 + g * 16) ^ ((r16 & 7) << 4)));
      #pragma unroll
      for (int dt = 0; dt < 4; dt++){
        int vrow = dt * 16 + r16;
        bf16x8 vb = *(const bf16x8*)((char*)vs + vrow * 128 + ((kt * 64 + g * 16) ^ ((vrow & 7) << 4)));
        o[dt] = mfma16(pa, vb, o[dt]);
      }
    }
  }

  l_i += __shfl_xor(l_i, 16);
  l_i += __shfl_xor(l_i, 32);
  float lf[4];
  #pragma unroll
  for (int r = 0; r < 4; r++) lf[r] = 1.f / __shfl(l_i, 4 * g + r);
  const int bidx = bh / 12, h = bh - bidx * 12;
  #pragma unroll
  for (int dt = 0; dt < 4; dt++){
    int d = dt * 16 + r16;
    #pragma unroll
    for (int r = 0; r < 4; r++){
      int i = qb * 64 + w * 16 + 4 * g + r;
      ao[(size_t)(bidx * 1024 + i) * 768 + h * 64 + d] = f2bf(o[dt][r] * lf[r]);
    }
  }
}

// ---------------------------------------------------------------------------
// Output projection (256x128 8-phase): out = attn_out @ proj_w^T + proj_b
// ---------------------------------------------------------------------------
__global__ __launch_bounds__(512, 4) void proj_gemm(
    const unsigned short* __restrict__ aob, const unsigned short* __restrict__ pwb,
    const float* __restrict__ pb, float* __restrict__ out){
  __shared__ __align__(16) char smem[49152];
  f32x4 acc[8][2];
  #pragma unroll
  for (int i = 0; i < 8; i++)
    #pragma unroll
    for (int j = 0; j < 2; j++){
      acc[i][j][0] = 0.f; acc[i][j][1] = 0.f; acc[i][j][2] = 0.f; acc[i][j][3] = 0.f;
    }
  const int m0 = blockIdx.y * 256, n0 = blockIdx.x * 128;
  gemm_core_mn(aob, pwb, m0, n0, 768, smem, acc);

  const int tid = threadIdx.x, lane = tid & 63, w = tid >> 6;
  const int g = lane >> 4, r16 = lane & 15;
  const int wr = w >> 2, wc = w & 3;
  #pragma unroll
  for (int mi = 0; mi < 8; mi++){
    int grow = m0 + wr * 128 + mi * 16 + r16;
    #pragma unroll
    for (int ni = 0; ni < 2; ni++){
      int gcol0 = n0 + wc * 32 + ni * 16 + 4 * g;
      float4 b4 = *(const float4*)(pb + gcol0);
      f32x4 v = acc[mi][ni];
      float4 ov;
      ov.x = v[0] + b4.x; ov.y = v[1] + b4.y;
      ov.z = v[2] + b4.z; ov.w = v[3] + b4.w;
      *(float4*)(out + (size_t)grow * 768 + gcol0) = ov;
    }
  }
}

// ---------------------------------------------------------------------------
extern "C" void kernel_launch(void* const* d_in, const int* in_sizes, int n_in,
                              void* d_out, int out_size, void* d_ws, size_t ws_size,
                              hipStream_t stream){
  const float* x      = (const float*)d_in[0];
  const float* qkv_w  = (const float*)d_in[1];
  const float* rpe    = (const float*)d_in[2];
  const int*   rp     = (const int*)d_in[3];
  const float* proj_w = (const float*)d_in[4];
  const float* proj_b = (const float*)d_in[5];
  float* out = (float*)d_out;
  char* ws = (char*)d_ws;

  unsigned short* xb  = (unsigned short*)(ws);               // 25,165,824 B
  unsigned short* wb  = (unsigned short*)(ws + 25165824);    //  3,538,944 B
  unsigned short* pwb = (unsigned short*)(ws + 28704768);    //  1,179,648 B
  unsigned char*  rp8 = (unsigned char*) (ws + 29884416);    //  1,048,576 B
  unsigned short* q_s = (unsigned short*)(ws + 30932992);    // 25,165,824 B
  unsigned short* k_s = (unsigned short*)(ws + 56098816);    // 25,165,824 B
  unsigned short* v_t = (unsigned short*)(ws + 81264640);    // 25,165,824 B
  unsigned short* aob = (unsigned short*)(ws + 106430464);   // 25,165,824 B -> 131,596,288 total

  prep_kernel<<<2048, 256, 0, stream>>>(x, qkv_w, proj_w, rp, xb, wb, pwb, rp8);
  qkv_gemm<<<dim3(18, 64), 512, 0, stream>>>(xb, wb, q_s, k_s, v_t);
  attn_kernel<<<dim3(16, 192), 256, 0, stream>>>(q_s, k_s, v_t, rp8, rpe, aob);
  proj_gemm<<<dim3(6, 64), 512, 0, stream>>>(aob, pwb, proj_b, out);
}

// Round 17
// 278.861 us; speedup vs baseline: 1.0275x; 1.0275x over previous
//
#include <hip/hip_runtime.h>

typedef short bf16x8 __attribute__((ext_vector_type(8)));
typedef float f32x4 __attribute__((ext_vector_type(4)));

// Problem constants
// B=16, N=1024, D=768, H=12, HD=64, NUM_BUCKETS=49, SCALE=0.125
// Q is pre-scaled by SCALE*log2(e) so softmax runs in exp2 domain.
#define QSCALE 0.1803368801111204f

__device__ __forceinline__ unsigned short f2bf(float f){
  unsigned u = __float_as_uint(f);
  u = (u + 0x7fffu + ((u >> 16) & 1u)) >> 16;   // round-nearest-even
  return (unsigned short)u;
}
__device__ __forceinline__ f32x4 mfma16(bf16x8 a, bf16x8 b, f32x4 c){
  return __builtin_amdgcn_mfma_f32_16x16x32_bf16(a, b, c, 0, 0, 0);
}
__device__ __forceinline__ void gload_lds16(const void* g, void* l){
  __builtin_amdgcn_global_load_lds((__attribute__((address_space(1))) void*)(g),
                                   (__attribute__((address_space(3))) void*)(l), 16, 0, 0);
}
__device__ __forceinline__ unsigned cvt_pk_bf16(float lo, float hi){
  unsigned r;
  asm("v_cvt_pk_bf16_f32 %0, %1, %2" : "=v"(r) : "v"(lo), "v"(hi));
  return r;
}
// v_exp_f32 computes 2^x natively on gfx950 (cdna4_isa §3)
__device__ __forceinline__ float exp2_fast(float x){
  float r;
  asm("v_exp_f32 %0, %1" : "=v"(r) : "v"(x));
  return r;
}

// ---------------------------------------------------------------------------
// prep: f32 -> bf16 conversions + rp_bucket -> pre-swizzled byte offsets
// ---------------------------------------------------------------------------
__global__ __launch_bounds__(256) void prep_kernel(
    const float* __restrict__ x, const float* __restrict__ qw,
    const float* __restrict__ pw, const int* __restrict__ rp,
    unsigned short* __restrict__ xb, unsigned short* __restrict__ wb,
    unsigned short* __restrict__ pwb, unsigned char* __restrict__ rp8){
  const int T1 = 3145728;            // 16384*768/4
  const int T2 = T1 + 442368;        // + 2304*768/4
  const int T3 = T2 + 147456;        // + 768*768/4
  const int T4 = T3 + 262144;        // + 1024*1024/4
  for (int t = blockIdx.x * 256 + threadIdx.x; t < T4; t += gridDim.x * 256){
    if (t < T3){
      const float4* src; ushort4* dst; int off;
      if (t < T1){ src = (const float4*)x;  dst = (ushort4*)xb;  off = t; }
      else if (t < T2){ src = (const float4*)qw; dst = (ushort4*)wb;  off = t - T1; }
      else { src = (const float4*)pw; dst = (ushort4*)pwb; off = t - T2; }
      float4 v = src[off];
      ushort4 u;
      u.x = f2bf(v.x); u.y = f2bf(v.y); u.z = f2bf(v.z); u.w = f2bf(v.w);
      dst[off] = u;
    } else {
      int off = t - T3;
      int4 v = ((const int4*)rp)[off];
      int row = (off * 4) >> 10;               // all 4 j's share the row
      int sw = (row & 7) << 4;
      uchar4 u;
      u.x = (unsigned char)((v.x << 1) ^ sw);
      u.y = (unsigned char)((v.y << 1) ^ sw);
      u.z = (unsigned char)((v.z << 1) ^ sw);
      u.w = (unsigned char)((v.w << 1) ^ sw);
      ((uchar4*)rp8)[off] = u;
    }
  }
}

// ---------------------------------------------------------------------------
// 256x256 8-phase GEMM core (plain-HIP port of the m201 schedule, BK=32 so
// LDS fits 64KB static). 512 threads = 8 waves (2 wr x 4 wc); per-wave C-tile
// 128x64 = acc[8][4]. NT = K/32 K-tiles; 2 tiles/iteration, 8 phases.
// Counted vmcnt(2) at phase 0/4 only; raw s_barrier x4/iter (no drain-0).
// T5: s_setprio(1) around each 8-MFMA cluster (m218b: +21-25% on 8-phase).
// LDS tile layout: [128 lines][128B], each line = 2 rows of 32 bf16, chunks
// XOR-swizzled by (line&7) (stage source pre-swizzled, read swizzled).
// MFMA operands swapped (b first) -> reg r = consecutive C columns.
// ---------------------------------------------------------------------------
__device__ __forceinline__ void stage_half256(
    const unsigned short* __restrict__ M, int r0, int K, int kt, int half,
    char* dst, int tid){
  int ci = half * 512 + tid;          // chunk id within 16KB tile (1024 chunks)
  int lr = ci >> 3, s = ci & 7;
  int cc = s ^ (lr & 7);
  int grow = lr * 2 + (cc >> 2);
  int gk = (cc & 3) * 8;
  gload_lds16(M + (size_t)(r0 + grow) * K + kt * 32 + gk, dst + ci * 16);
}

__device__ __forceinline__ void gemm_core256(
    const unsigned short* __restrict__ A, const unsigned short* __restrict__ Bm,
    int m0, int n0, int K, char* smem, f32x4 (&acc)[8][4]){
  const int tid = threadIdx.x, lane = tid & 63;
  const int w = tid >> 6, g = lane >> 4, r16 = lane & 15;
  const int wr = w >> 2, wc = w & 3;
  const int NT = K >> 5;
  char* Ab0 = smem;            char* Ab1 = smem + 16384;
  char* Bb0 = smem + 32768;    char* Bb1 = smem + 49152;

  // prologue: B(0), A(0), B(1) -> 6 outstanding loads/thread
  stage_half256(Bm, n0, K, 0, 0, Bb0, tid);
  stage_half256(Bm, n0, K, 0, 1, Bb0, tid);
  stage_half256(A,  m0, K, 0, 0, Ab0, tid);
  stage_half256(A,  m0, K, 0, 1, Ab0, tid);
  stage_half256(Bm, n0, K, 1, 0, Bb1, tid);
  stage_half256(Bm, n0, K, 1, 1, Bb1, tid);

  const int arb = wr * 128 + r16;
  const int brb = wc * 64 + r16;
  bf16x8 bq[4];

#define LOADB_(buf) { \
  _Pragma("unroll") \
  for (int ni = 0; ni < 4; ni++){ \
    int row = brb + ni * 16; int lr = row >> 1; \
    bq[ni] = *(const bf16x8*)((buf) + lr * 128 + ((((row & 1) << 6) + g * 16) ^ ((lr & 7) << 4))); } }
#define QUAD_(buf, p) { \
  int ra = arb + (2 * (p)) * 16; int rb = ra + 16; \
  int la = ra >> 1, lb = rb >> 1; \
  bf16x8 afa = *(const bf16x8*)((buf) + la * 128 + ((((ra & 1) << 6) + g * 16) ^ ((la & 7) << 4))); \
  bf16x8 afb = *(const bf16x8*)((buf) + lb * 128 + ((((rb & 1) << 6) + g * 16) ^ ((lb & 7) << 4))); \
  __builtin_amdgcn_s_setprio(1); \
  _Pragma("unroll") \
  for (int ni = 0; ni < 4; ni++){ \
    acc[2 * (p)][ni]     = mfma16(bq[ni], afa, acc[2 * (p)][ni]); \
    acc[2 * (p) + 1][ni] = mfma16(bq[ni], afb, acc[2 * (p) + 1][ni]); } \
  __builtin_amdgcn_s_setprio(0); }

  for (int T = 0; T < NT; T += 2){
    int t2 = T + 2, t3 = T + 3;
    if (t2 >= NT) t2 -= NT;
    if (t3 >= NT) t3 -= NT;
    // loop top: B(T),A(T) landed (leave B(T+1) in flight)
    asm volatile("s_waitcnt vmcnt(2) lgkmcnt(0)" ::: "memory");
    __builtin_amdgcn_s_barrier();
    __builtin_amdgcn_sched_barrier(0);
    // ph0
    stage_half256(A, m0, K, T + 1, 0, Ab1, tid);
    LOADB_(Bb0); QUAD_(Ab0, 0);
    // ph1
    stage_half256(A, m0, K, T + 1, 1, Ab1, tid);
    QUAD_(Ab0, 1);
    asm volatile("s_waitcnt lgkmcnt(0)" ::: "memory");
    __builtin_amdgcn_s_barrier();            // frees Bb0 for restage
    __builtin_amdgcn_sched_barrier(0);
    // ph2
    stage_half256(Bm, n0, K, t2, 0, Bb0, tid);
    QUAD_(Ab0, 2);
    // ph3
    stage_half256(Bm, n0, K, t2, 1, Bb0, tid);
    QUAD_(Ab0, 3);
    // B(T+1),A(T+1) landed (leave B(T+2) in flight)
    asm volatile("s_waitcnt vmcnt(2) lgkmcnt(0)" ::: "memory");
    __builtin_amdgcn_s_barrier();
    __builtin_amdgcn_sched_barrier(0);
    // ph4
    stage_half256(A, m0, K, t2, 0, Ab0, tid);
    LOADB_(Bb1); QUAD_(Ab1, 0);
    // ph5
    stage_half256(A, m0, K, t2, 1, Ab0, tid);
    QUAD_(Ab1, 1);
    asm volatile("s_waitcnt lgkmcnt(0)" ::: "memory");
    __builtin_amdgcn_s_barrier();            // frees Bb1 for restage
    __builtin_amdgcn_sched_barrier(0);
    // ph6
    stage_half256(Bm, n0, K, t3, 0, Bb1, tid);
    QUAD_(Ab1, 2);
    // ph7
    stage_half256(Bm, n0, K, t3, 1, Bb1, tid);
    QUAD_(Ab1, 3);
  }
#undef LOADB_
#undef QUAD_
}

// ---------------------------------------------------------------------------
// QKV projection (256² 8-phase): qkv = x @ qkv_w^T ; route to
// Q(*QSCALE)[B,H,N,HD], K[B,H,N,HD], V^T[B,H,HD,N], bf16.
// Each 256-wide n-tile lies wholly in one of Q/K/V (768 = 3 x 256).
// ---------------------------------------------------------------------------
__global__ __launch_bounds__(512, 2) void qkv_gemm(
    const unsigned short* __restrict__ xb, const unsigned short* __restrict__ wb,
    unsigned short* __restrict__ q_s, unsigned short* __restrict__ k_s,
    unsigned short* __restrict__ v_t){
  __shared__ __align__(16) char smem[65536];
  f32x4 acc[8][4];
  #pragma unroll
  for (int i = 0; i < 8; i++)
    #pragma unroll
    for (int j = 0; j < 4; j++){
      acc[i][j][0] = 0.f; acc[i][j][1] = 0.f; acc[i][j][2] = 0.f; acc[i][j][3] = 0.f;
    }
  const int m0 = blockIdx.y * 256, n0 = blockIdx.x * 256;
  gemm_core256(xb, wb, m0, n0, 768, smem, acc);

  const int tid = threadIdx.x, lane = tid & 63, w = tid >> 6;
  const int g = lane >> 4, r16 = lane & 15;
  const int wr = w >> 2, wc = w & 3;
  const int sel = n0 / 768;                       // block-uniform
  #pragma unroll
  for (int mi = 0; mi < 8; mi++){
    int grow = m0 + wr * 128 + mi * 16 + r16;     // 0..16383 = [16][1024]
    int bb = grow >> 10, ii = grow & 1023;
    #pragma unroll
    for (int ni = 0; ni < 4; ni++){
      int gcol0 = n0 + wc * 64 + ni * 16 + 4 * g; // 4-aligned, within one head
      int rem = gcol0 - sel * 768;
      int h = rem >> 6, hd0 = rem & 63;
      size_t base = ((size_t)(bb * 12 + h)) << 16;   // *1024*64
      f32x4 v = acc[mi][ni];
      if (sel == 0){
        ushort4 u;
        u.x = f2bf(v[0] * QSCALE); u.y = f2bf(v[1] * QSCALE);
        u.z = f2bf(v[2] * QSCALE); u.w = f2bf(v[3] * QSCALE);
        *(ushort4*)(q_s + base + ((size_t)ii << 6) + hd0) = u;
      } else if (sel == 1){
        ushort4 u;
        u.x = f2bf(v[0]); u.y = f2bf(v[1]); u.z = f2bf(v[2]); u.w = f2bf(v[3]);
        *(ushort4*)(k_s + base + ((size_t)ii << 6) + hd0) = u;
      } else {
        #pragma unroll
        for (int r = 0; r < 4; r++)
          v_t[base + ((size_t)(hd0 + r) << 10) + ii] = f2bf(v[r]);
      }
    }
  }
}

// ---------------------------------------------------------------------------
// Flash attention with relative-position bias (exp2-domain online softmax,
// defer-max THR=8, pre-swizzled bucket byte offsets, bf16 bias table).
// R7/R13 champion: 64 q-rows/block, 4 waves x 16 rows, LDS 32768 B. FROZEN.
// ---------------------------------------------------------------------------
__global__ __launch_bounds__(256) void attn_kernel(
    const unsigned short* __restrict__ q_s, const unsigned short* __restrict__ k_s,
    const unsigned short* __restrict__ v_t, const unsigned char* __restrict__ rp8,
    const float* __restrict__ rpe, unsigned short* __restrict__ ao){
  __shared__ __align__(16) char smem[32768];
  const int tid = threadIdx.x, lane = tid & 63, w = tid >> 6;
  const int g = lane >> 4, r16 = lane & 15;
  const int qb = blockIdx.x, bh = blockIdx.y;
  const size_t bh_base = (size_t)bh << 16;   // *1024*64 elements

  const int i_loc = w * 16 + r16;
  const size_t qoff = bh_base + ((size_t)(qb * 64 + i_loc) << 6);
  bf16x8 qf0 = *(const bf16x8*)(q_s + qoff + g * 8);
  bf16x8 qf1 = *(const bf16x8*)(q_s + qoff + 32 + g * 8);

  // bias[i][c] = q_i . rpe_c via MFMA; bf16, swizzled; wave-private
  char* bias_lds = smem + 24576;
  const int s16 = (r16 & 7) << 4;
  #pragma unroll
  for (int jt = 0; jt < 4; jt++){
    int crow = jt * 16 + r16;
    bf16x8 a0, a1;
    #pragma unroll
    for (int e = 0; e < 8; e++){ a0[e] = 0; a1[e] = 0; }
    if (crow < 49){
      const float* rr = rpe + crow * 64 + g * 8;
      float4 x0 = *(const float4*)(rr);
      float4 x1 = *(const float4*)(rr + 4);
      float4 y0 = *(const float4*)(rr + 32);
      float4 y1 = *(const float4*)(rr + 36);
      a0[0]=f2bf(x0.x); a0[1]=f2bf(x0.y); a0[2]=f2bf(x0.z); a0[3]=f2bf(x0.w);
      a0[4]=f2bf(x1.x); a0[5]=f2bf(x1.y); a0[6]=f2bf(x1.z); a0[7]=f2bf(x1.w);
      a1[0]=f2bf(y0.x); a1[1]=f2bf(y0.y); a1[2]=f2bf(y0.z); a1[3]=f2bf(y0.w);
      a1[4]=f2bf(y1.x); a1[5]=f2bf(y1.y); a1[6]=f2bf(y1.z); a1[7]=f2bf(y1.w);
    }
    f32x4 z = {0.f, 0.f, 0.f, 0.f};
    z = mfma16(a0, qf0, z);
    z = mfma16(a1, qf1, z);
    uint2 u; u.x = cvt_pk_bf16(z[0], z[1]); u.y = cvt_pk_bf16(z[2], z[3]);
    *(uint2*)(bias_lds + i_loc * 128 + ((jt * 32 + 8 * g) ^ s16)) = u;
  }

  unsigned short* ks = (unsigned short*)smem;
  unsigned short* vs = (unsigned short*)(smem + 8192);
  char* pbuf = smem + 16384 + w * 2048;
  const char* browb = bias_lds + i_loc * 128;

  const int ci0 = tid, ci1 = 256 + tid;
  const int row0 = ci0 >> 3, sc0 = (ci0 & 7) ^ (row0 & 7);
  const int row1 = ci1 >> 3, sc1 = (ci1 & 7) ^ (row1 & 7);
  const char* kp0 = (const char*)(k_s + bh_base) + row0 * 128 + sc0 * 16;
  const char* kp1 = (const char*)(k_s + bh_base) + row1 * 128 + sc1 * 16;
  const char* vp0 = (const char*)(v_t + bh_base) + row0 * 2048 + sc0 * 16;
  const char* vp1 = (const char*)(v_t + bh_base) + row1 * 2048 + sc1 * 16;
  char* kl0 = (char*)smem + w * 1024;
  char* kl1 = (char*)smem + 4096 + w * 1024;
  char* vl0 = (char*)smem + 8192 + w * 1024;
  char* vl1 = (char*)smem + 12288 + w * 1024;
  const unsigned char* rprow = rp8 + ((size_t)(qb * 64 + i_loc) << 10);

  f32x4 o[4];
  #pragma unroll
  for (int dt = 0; dt < 4; dt++){ o[dt][0]=0.f; o[dt][1]=0.f; o[dt][2]=0.f; o[dt][3]=0.f; }
  float m_i = -INFINITY, l_i = 0.f;

  for (int kb = 0; kb < 16; kb++){
    __syncthreads();
    gload_lds16(kp0, kl0);
    gload_lds16(kp1, kl1);
    gload_lds16(vp0, vl0);
    gload_lds16(vp1, vl1);
    kp0 += 8192; kp1 += 8192; vp0 += 128; vp1 += 128;
    __syncthreads();

    f32x4 st[4];
    #pragma unroll
    for (int jt = 0; jt < 4; jt++){
      int krow = jt * 16 + r16;
      int sw = (krow & 7) << 4;
      bf16x8 ka0 = *(const bf16x8*)((char*)ks + krow * 128 + ((g * 16) ^ sw));
      bf16x8 ka1 = *(const bf16x8*)((char*)ks + krow * 128 + ((64 + g * 16) ^ sw));
      f32x4 z = {0.f, 0.f, 0.f, 0.f};
      z = mfma16(ka0, qf0, z);
      z = mfma16(ka1, qf1, z);
      st[jt] = z;
    }
    #pragma unroll
    for (int jt = 0; jt < 4; jt++){
      unsigned bu = *(const unsigned*)(rprow + kb * 64 + jt * 16 + g * 4);
      st[jt][0] += __uint_as_float((unsigned)*(const unsigned short*)(browb + (bu & 0xff)) << 16);
      st[jt][1] += __uint_as_float((unsigned)*(const unsigned short*)(browb + ((bu >> 8) & 0xff)) << 16);
      st[jt][2] += __uint_as_float((unsigned)*(const unsigned short*)(browb + ((bu >> 16) & 0xff)) << 16);
      st[jt][3] += __uint_as_float((unsigned)*(const unsigned short*)(browb + (bu >> 24)) << 16);
    }
    float tmax = -INFINITY;
    #pragma unroll
    for (int jt = 0; jt < 4; jt++)
      tmax = fmaxf(tmax, fmaxf(fmaxf(st[jt][0], st[jt][1]), fmaxf(st[jt][2], st[jt][3])));
    tmax = fmaxf(tmax, __shfl_xor(tmax, 16));
    tmax = fmaxf(tmax, __shfl_xor(tmax, 32));
    const bool skip = __all(tmax <= m_i + 8.f);
    if (!skip){
      float mnew = fmaxf(m_i, tmax);
      float alpha = exp2_fast(m_i - mnew);
      m_i = mnew;
      l_i *= alpha;
      float af[4];
      #pragma unroll
      for (int r = 0; r < 4; r++) af[r] = __shfl(alpha, 4 * g + r);
      #pragma unroll
      for (int dt = 0; dt < 4; dt++){
        o[dt][0] *= af[0]; o[dt][1] *= af[1]; o[dt][2] *= af[2]; o[dt][3] *= af[3];
      }
    }
    #pragma unroll
    for (int jt = 0; jt < 4; jt++){
      float p0 = exp2_fast(st[jt][0] - m_i);
      float p1 = exp2_fast(st[jt][1] - m_i);
      float p2 = exp2_fast(st[jt][2] - m_i);
      float p3 = exp2_fast(st[jt][3] - m_i);
      l_i += (p0 + p1) + (p2 + p3);
      uint2 u; u.x = cvt_pk_bf16(p0, p1); u.y = cvt_pk_bf16(p2, p3);
      *(uint2*)(pbuf + r16 * 128 + ((jt * 32 + g * 8) ^ ((r16 & 7) << 4))) = u;
    }
    #pragma unroll
    for (int kt = 0; kt < 2; kt++){
      bf16x8 pa = *(const bf16x8*)(pbuf + r16 * 128 + ((kt * 64 + g * 16) ^ ((r16 & 7) << 4)));
      #pragma unroll
      for (int dt = 0; dt < 4; dt++){
        int vrow = dt * 16 + r16;
        bf16x8 vb = *(const bf16x8*)((char*)vs + vrow * 128 + ((kt * 64 + g * 16) ^ ((vrow & 7) << 4)));
        o[dt] = mfma16(pa, vb, o[dt]);
      }
    }
  }

  l_i += __shfl_xor(l_i, 16);
  l_i += __shfl_xor(l_i, 32);
  float lf[4];
  #pragma unroll
  for (int r = 0; r < 4; r++) lf[r] = 1.f / __shfl(l_i, 4 * g + r);
  const int bidx = bh / 12, h = bh - bidx * 12;
  #pragma unroll
  for (int dt = 0; dt < 4; dt++){
    int d = dt * 16 + r16;
    #pragma unroll
    for (int r = 0; r < 4; r++){
      int i = qb * 64 + w * 16 + 4 * g + r;
      ao[(size_t)(bidx * 1024 + i) * 768 + h * 64 + d] = f2bf(o[dt][r] * lf[r]);
    }
  }
}

// ---------------------------------------------------------------------------
// Output projection (256² 8-phase): out = attn_out @ proj_w^T + proj_b (f32)
// ---------------------------------------------------------------------------
__global__ __launch_bounds__(512, 2) void proj_gemm(
    const unsigned short* __restrict__ aob, const unsigned short* __restrict__ pwb,
    const float* __restrict__ pb, float* __restrict__ out){
  __shared__ __align__(16) char smem[65536];
  f32x4 acc[8][4];
  #pragma unroll
  for (int i = 0; i < 8; i++)
    #pragma unroll
    for (int j = 0; j < 4; j++){
      acc[i][j][0] = 0.f; acc[i][j][1] = 0.f; acc[i][j][2] = 0.f; acc[i][j][3] = 0.f;
    }
  const int m0 = blockIdx.y * 256, n0 = blockIdx.x * 256;
  gemm_core256(aob, pwb, m0, n0, 768, smem, acc);

  const int tid = threadIdx.x, lane = tid & 63, w = tid >> 6;
  const int g = lane >> 4, r16 = lane & 15;
  const int wr = w >> 2, wc = w & 3;
  #pragma unroll
  for (int mi = 0; mi < 8; mi++){
    int grow = m0 + wr * 128 + mi * 16 + r16;
    #pragma unroll
    for (int ni = 0; ni < 4; ni++){
      int gcol0 = n0 + wc * 64 + ni * 16 + 4 * g;
      float4 b4 = *(const float4*)(pb + gcol0);
      f32x4 v = acc[mi][ni];
      float4 ov;
      ov.x = v[0] + b4.x; ov.y = v[1] + b4.y;
      ov.z = v[2] + b4.z; ov.w = v[3] + b4.w;
      *(float4*)(out + (size_t)grow * 768 + gcol0) = ov;
    }
  }
}

// ---------------------------------------------------------------------------
extern "C" void kernel_launch(void* const* d_in, const int* in_sizes, int n_in,
                              void* d_out, int out_size, void* d_ws, size_t ws_size,
                              hipStream_t stream){
  const float* x      = (const float*)d_in[0];
  const float* qkv_w  = (const float*)d_in[1];
  const float* rpe    = (const float*)d_in[2];
  const int*   rp     = (const int*)d_in[3];
  const float* proj_w = (const float*)d_in[4];
  const float* proj_b = (const float*)d_in[5];
  float* out = (float*)d_out;
  char* ws = (char*)d_ws;

  unsigned short* xb  = (unsigned short*)(ws);               // 25,165,824 B
  unsigned short* wb  = (unsigned short*)(ws + 25165824);    //  3,538,944 B
  unsigned short* pwb = (unsigned short*)(ws + 28704768);    //  1,179,648 B
  unsigned char*  rp8 = (unsigned char*) (ws + 29884416);    //  1,048,576 B
  unsigned short* q_s = (unsigned short*)(ws + 30932992);    // 25,165,824 B
  unsigned short* k_s = (unsigned short*)(ws + 56098816);    // 25,165,824 B
  unsigned short* v_t = (unsigned short*)(ws + 81264640);    // 25,165,824 B
  unsigned short* aob = (unsigned short*)(ws + 106430464);   // 25,165,824 B -> 131,596,288 total

  prep_kernel<<<2048, 256, 0, stream>>>(x, qkv_w, proj_w, rp, xb, wb, pwb, rp8);
  qkv_gemm<<<dim3(9, 64), 512, 0, stream>>>(xb, wb, q_s, k_s, v_t);
  attn_kernel<<<dim3(16, 192), 256, 0, stream>>>(q_s, k_s, v_t, rp8, rpe, aob);
  proj_gemm<<<dim3(3, 64), 512, 0, stream>>>(aob, pwb, proj_b, out);
}